// Round 14
// baseline (661.972 us; speedup 1.0000x reference)
//
#include <hip/hip_runtime.h>

// LIF sim, three-phase:
//   0) split_h: pre-split h1 into bf16 hi/lo planes in d_ws ([kt][nb] 8KB
//      chunks, the gemm's swizzled B-LDS image).
//   1) lif_gemm<true>: aS = X @ H via bf16 3-product-split MFMA
//      (xh·hh + xh·hl + xl·hh), f32 accumulate, cvt_pk A-split, conflict-free
//      B copy, XCD swizzle, setprio around MFMA cluster. (R11/R13 verified.)
//   2) lif_scan: 500-step LIF scan, ONE WAVE PER BATCH ROW (8 neurons/lane):
//      spike mask exchanged via 8 in-register ballots (bit-transposed), no
//      LDS, no barrier. f64 state; same per-neuron arithmetic as verified.
typedef __attribute__((ext_vector_type(8))) short short8;
typedef __attribute__((ext_vector_type(4))) float f32x4;

constexpr int BSZ = 256;
constexpr int NRN = 512;
constexpr int KIN = 512;
constexpr int TT  = 500;
constexpr int BM  = 128;   // m-tile (rows of x)
constexpr int BN  = 128;   // n-tile (neuron cols)
constexpr int KT  = 32;    // k-tile
constexpr int NBLK = (TT * BSZ / BM) * (NRN / BN);   // 4000
constexpr size_t WS_NEED = (size_t)2 * KIN * NRN * sizeof(unsigned short); // 1 MB

__device__ __forceinline__ unsigned short bf16rne(float f) {
    unsigned u = __float_as_uint(f);
    u += 0x7FFFu + ((u >> 16) & 1u);
    return (unsigned short)(u >> 16);
}
__device__ __forceinline__ float bf16f(unsigned short s) {
    return __uint_as_float(((unsigned)s) << 16);
}
// packed RNE bf16 pair: low16 = bf16(a), high16 = bf16(b). Bit-identical to bf16rne.
__device__ __forceinline__ unsigned cvtpk(float a, float b) {
    unsigned r;
    asm("v_cvt_pk_bf16_f32 %0, %1, %2" : "=v"(r) : "v"(a), "v"(b));
    return r;
}

// h1[k][n] -> hi/lo bf16 planes, laid out as the gemm's B-LDS image:
// chunk (kt*4+nb) of 8192 B; byte = ((nl*64+koct*16) ^ (((nl>>1)&3)<<4)) + 2*i
__global__ __launch_bounds__(512)
void split_h(const float* __restrict__ h1,
             unsigned short* __restrict__ wsH,
             unsigned short* __restrict__ wsL)
{
    const int k = blockIdx.x;          // 0..511
    const int n = threadIdx.x;         // 0..511 (coalesced read)
    const float v = h1[(size_t)k * NRN + n];
    const unsigned short h  = bf16rne(v);
    const unsigned short lo = bf16rne(v - bf16f(h));
    const int kt = k >> 5, koct = (k >> 3) & 3, i = k & 7;
    const int nb = n >> 7, nl = n & 127;
    const int byte = (kt * 4 + nb) * 8192 +
                     ((nl * 64 + koct * 16) ^ (((nl >> 1) & 3) << 4)) + i * 2;
    *reinterpret_cast<unsigned short*>((char*)wsH + byte) = h;
    *reinterpret_cast<unsigned short*>((char*)wsL + byte) = lo;
}

template<bool PS>
__global__ __launch_bounds__(256)
void lif_gemm(const float* __restrict__ x,
              const float* __restrict__ h1,
              const unsigned short* __restrict__ wsH,
              const unsigned short* __restrict__ wsL,
              float* __restrict__ out)
{
    // bf16 tiles, XOR-swizzled (byte ^= ((row>>1)&3)<<4): 4 x 8 KB = 32 KB
    __shared__ short AhS[BM * KT], AlS[BM * KT], BhS[BN * KT], BlS[BN * KT];

    const int tid  = threadIdx.x;
    const int l    = tid & 63;
    const int w    = tid >> 6;           // wave 0..3
    const int wm   = (w & 1) * 64;       // wave m-offset
    const int wn   = (w >> 1) * 64;      // wave n-offset
    const int lrow = l & 15;
    const int loct = l >> 4;             // k-octet 0..3

    // XCD-chunked bijective swizzle: 4000 = 8 x 500, 500 % 4 == 0 so the
    // 4 n-blocks of each m-tile stay inside one XCD's chunk (shared L2).
    const int nid = (blockIdx.x & 7) * (NBLK / 8) + (blockIdx.x >> 3);
    const size_t m0 = (size_t)(nid >> 2) * BM;
    const int    nb = nid & 3;
    const int    n0 = nb * BN;

    f32x4 acc[4][4];
    #pragma unroll
    for (int i = 0; i < 4; ++i)
        #pragma unroll
        for (int j = 0; j < 4; ++j) acc[i][j] = (f32x4)0.0f;

    for (int kt = 0; kt < KIN / KT; ++kt) {
        // ---- stage B (independent loads issue first, overlap A conversion) ----
        if (PS) {
            // linear conflict-free copy: 16B/lane consecutive
            const float4* sH = reinterpret_cast<const float4*>(
                (const char*)wsH + (kt * 4 + nb) * 8192);
            const float4* sL = reinterpret_cast<const float4*>(
                (const char*)wsL + (kt * 4 + nb) * 8192);
            float4* dH = reinterpret_cast<float4*>(BhS);
            float4* dL = reinterpret_cast<float4*>(BlS);
            dH[tid]       = sH[tid];
            dH[256 + tid] = sH[256 + tid];
            dL[tid]       = sL[tid];
            dL[256 + tid] = sL[256 + tid];
        } else {
            #pragma unroll
            for (int u2 = 0; u2 < 2; ++u2) {
                const int u = u2 * 256 + tid;          // 0..511
                const int nl = u & 127, koct = u >> 7; // n-local, k-octet
                short8 hh, hl;
                #pragma unroll
                for (int i = 0; i < 8; ++i) {          // coalesced across nl
                    const float v = h1[(size_t)(kt * KT + koct * 8 + i) * NRN + n0 + nl];
                    const unsigned short h = bf16rne(v);
                    hh[i] = (short)h;
                    hl[i] = (short)bf16rne(v - bf16f(h));
                }
                const int byte = (nl * 64 + koct * 16) ^ (((nl >> 1) & 3) << 4);
                *reinterpret_cast<short8*>((char*)BhS + byte) = hh;
                *reinterpret_cast<short8*>((char*)BlS + byte) = hl;
            }
        }
        // ---- stage A: x[m0..m0+128][kt*32..+32] -> bf16 split via cvt_pk ----
        #pragma unroll
        for (int u4 = 0; u4 < 4; ++u4) {
            const int u = u4 * 256 + tid;         // 0..1023
            const int row = u >> 3, slot = u & 7; // row 0..127, float4 slot 0..7
            const float4 xv = *reinterpret_cast<const float4*>(
                x + (m0 + row) * KIN + kt * KT + slot * 4);
            // hi plane (RNE, bit-identical to bf16rne)
            const unsigned h01 = cvtpk(xv.x, xv.y);
            const unsigned h23 = cvtpk(xv.z, xv.w);
            // residuals: bf16f(lo16)=bits<<16, bf16f(hi16)=bits&0xFFFF0000
            const float r0 = xv.x - __uint_as_float(h01 << 16);
            const float r1v = xv.y - __uint_as_float(h01 & 0xFFFF0000u);
            const float r2 = xv.z - __uint_as_float(h23 << 16);
            const float r3 = xv.w - __uint_as_float(h23 & 0xFFFF0000u);
            const unsigned l01 = cvtpk(r0, r1v);
            const unsigned l23 = cvtpk(r2, r3);
            const unsigned long long hb = (unsigned long long)h01 | ((unsigned long long)h23 << 32);
            const unsigned long long lb = (unsigned long long)l01 | ((unsigned long long)l23 << 32);
            const int byte = (row * 64 + slot * 8) ^ (((row >> 1) & 3) << 4);
            *reinterpret_cast<unsigned long long*>((char*)AhS + byte) = hb;
            *reinterpret_cast<unsigned long long*>((char*)AlS + byte) = lb;
        }
        __syncthreads();

        // ---- fragment loads (ds_read_b128) ----
        short8 ah[4], al[4], bh[4], bl[4];
        #pragma unroll
        for (int mi = 0; mi < 4; ++mi) {
            const int row  = wm + mi * 16 + lrow;
            const int byte = (row * 64 + loct * 16) ^ (((row >> 1) & 3) << 4);
            ah[mi] = *reinterpret_cast<const short8*>((const char*)AhS + byte);
            al[mi] = *reinterpret_cast<const short8*>((const char*)AlS + byte);
        }
        #pragma unroll
        for (int ni = 0; ni < 4; ++ni) {
            const int nn   = wn + ni * 16 + lrow;
            const int byte = (nn * 64 + loct * 16) ^ (((nn >> 1) & 3) << 4);
            bh[ni] = *reinterpret_cast<const short8*>((const char*)BhS + byte);
            bl[ni] = *reinterpret_cast<const short8*>((const char*)BlS + byte);
        }

        // ---- 48 MFMA: 3-product split (xl·hl dropped, ~1e-4 class) ----
        __builtin_amdgcn_s_setprio(1);
        #pragma unroll
        for (int mi = 0; mi < 4; ++mi)
            #pragma unroll
            for (int ni = 0; ni < 4; ++ni) {
                acc[mi][ni] = __builtin_amdgcn_mfma_f32_16x16x32_bf16(ah[mi], bh[ni], acc[mi][ni], 0, 0, 0);
                acc[mi][ni] = __builtin_amdgcn_mfma_f32_16x16x32_bf16(ah[mi], bl[ni], acc[mi][ni], 0, 0, 0);
                acc[mi][ni] = __builtin_amdgcn_mfma_f32_16x16x32_bf16(al[mi], bh[ni], acc[mi][ni], 0, 0, 0);
            }
        __builtin_amdgcn_s_setprio(0);
        __syncthreads();
    }

    // ---- epilogue: C/D layout col=lane&15, row=(lane>>4)*4+j (m89-verified) ----
    #pragma unroll
    for (int mi = 0; mi < 4; ++mi)
        #pragma unroll
        for (int j = 0; j < 4; ++j) {
            const size_t row = m0 + wm + mi * 16 + loct * 4 + j;
            float* op = out + row * NRN + n0 + wn + lrow;
            #pragma unroll
            for (int ni = 0; ni < 4; ++ni)
                op[ni * 16] = acc[mi][ni][j];
        }
}

// One wave per batch row: lane ln owns neurons ln*8..ln*8+7.
// Spike mask: mw[q] bit ln = spike of neuron ln*8+q (bit-transposed), built
// with 8 ballots per step. No LDS, no barrier — pure register dataflow.
__global__ __launch_bounds__(64)
void lif_scan(const float* __restrict__ r1,
              float* __restrict__ out)
{
    const int ln = threadIdx.x;      // lane 0..63
    const int b  = blockIdx.x;       // batch row
    const int n0 = ln * 8;
    constexpr size_t STEP = (size_t)BSZ * NRN;
    const size_t rowb = (size_t)b * NRN + n0;

    double csum[8], V[8], Is[8], Ir[8], cnt[8], steady[8];
    #pragma unroll
    for (int q = 0; q < 8; ++q) {
        csum[q] = 0.0; V[q] = 1.0; Is[q] = 0.0; Ir[q] = 0.0; cnt[q] = 0.0;
        steady[q] = 0.01 * (double)(n0 + q);
    }
    // ascending-j f64 column sums (dense recurrent fast path), 32B/lane loads
    for (int j = 0; j < KIN; ++j) {
        const float4 ra = *reinterpret_cast<const float4*>(r1 + (size_t)j * NRN + n0);
        const float4 rb = *reinterpret_cast<const float4*>(r1 + (size_t)j * NRN + n0 + 4);
        csum[0] += (double)ra.x; csum[1] += (double)ra.y;
        csum[2] += (double)ra.z; csum[3] += (double)ra.w;
        csum[4] += (double)rb.x; csum[5] += (double)rb.y;
        csum[6] += (double)rb.z; csum[7] += (double)rb.w;
    }

    unsigned long long mw[8];
    #pragma unroll
    for (int q = 0; q < 8; ++q) mw[q] = 0ULL;

    constexpr double kS = 0.1, kN = 0.05, DT = 0.001;

    // depth-4 prefetch of aS (2 float4 per step, named regs)
    float4 p0a, p0b, p1a, p1b, p2a, p2b, p3a, p3b;
    p0a = *reinterpret_cast<const float4*>(out + 0 * STEP + rowb);
    p0b = *reinterpret_cast<const float4*>(out + 0 * STEP + rowb + 4);
    p1a = *reinterpret_cast<const float4*>(out + 1 * STEP + rowb);
    p1b = *reinterpret_cast<const float4*>(out + 1 * STEP + rowb + 4);
    p2a = *reinterpret_cast<const float4*>(out + 2 * STEP + rowb);
    p2b = *reinterpret_cast<const float4*>(out + 2 * STEP + rowb + 4);
    p3a = *reinterpret_cast<const float4*>(out + 3 * STEP + rowb);
    p3b = *reinterpret_cast<const float4*>(out + 3 * STEP + rowb + 4);

#define LIF_STEP(T, PA, PB)                                                   \
    {                                                                         \
        const int t_ = (T);                                                   \
        int pc = 0;                                                           \
        _Pragma("unroll")                                                     \
        for (int q = 0; q < 8; ++q) pc += __popcll(mw[q]);                    \
        double aR[8];                                                         \
        if (pc == 512) {                                                      \
            _Pragma("unroll") for (int q = 0; q < 8; ++q) aR[q] = csum[q];    \
        } else if (pc == 0) {                                                 \
            _Pragma("unroll") for (int q = 0; q < 8; ++q) aR[q] = 0.0;        \
        } else {                                                              \
            _Pragma("unroll") for (int q = 0; q < 8; ++q) aR[q] = 0.0;        \
            _Pragma("unroll")                                                 \
            for (int q2 = 0; q2 < 8; ++q2) {                                  \
                unsigned long long m_ = mw[q2];                               \
                while (m_) {             /* wave-uniform loop */              \
                    const int j = (__builtin_ctzll(m_) << 3) + q2;            \
                    const float4 ra = *reinterpret_cast<const float4*>(       \
                        r1 + (size_t)j * NRN + n0);                           \
                    const float4 rb = *reinterpret_cast<const float4*>(       \
                        r1 + (size_t)j * NRN + n0 + 4);                       \
                    aR[0] += (double)ra.x; aR[1] += (double)ra.y;             \
                    aR[2] += (double)ra.z; aR[3] += (double)ra.w;             \
                    aR[4] += (double)rb.x; aR[5] += (double)rb.y;             \
                    aR[6] += (double)rb.z; aR[7] += (double)rb.w;             \
                    m_ &= m_ - 1;                                             \
                }                                                             \
            }                                                                 \
        }                                                                     \
        const float aSv[8] = { (PA).x, (PA).y, (PA).z, (PA).w,                \
                               (PB).x, (PB).y, (PB).z, (PB).w };              \
        float sout[8];                                                        \
        unsigned spbits = 0;                                                  \
        _Pragma("unroll")                                                     \
        for (int q = 0; q < 8; ++q) {                                         \
            Is[q] = Is[q] - kS * Is[q] + (double)aSv[q];    /* gain_syn=1 */  \
            Ir[q] = Ir[q] - kS * Ir[q] + 0.5 * aR[q];       /* gain_rec  */   \
            double Vn = V[q] - kN * V[q] + DT * (Is[q] + Ir[q] + steady[q]);  \
            Vn = fmax(Vn, 0.0);                                               \
            const bool sp = (Vn - 1.0) > 0.0;                                 \
            cnt[q] = sp ? 2.0 : (cnt[q] - 1.0);             /* REFR = 2 */    \
            V[q] = sp ? 0.0 : ((cnt[q] <= 0.0) ? Vn : 0.0);                   \
            sout[q] = sp ? 1.0f : 0.0f;                                       \
            spbits |= (unsigned)sp << q;                                      \
        }                                                                     \
        _Pragma("unroll")                                                     \
        for (int q = 0; q < 8; ++q) mw[q] = __ballot((spbits >> q) & 1u);     \
        const float4 o0 = { sout[0], sout[1], sout[2], sout[3] };             \
        const float4 o1 = { sout[4], sout[5], sout[6], sout[7] };             \
        *reinterpret_cast<float4*>(out + (size_t)t_ * STEP + rowb)     = o0;  \
        *reinterpret_cast<float4*>(out + (size_t)t_ * STEP + rowb + 4) = o1;  \
    }

    for (int t4 = 0; t4 < TT; t4 += 4) {
        LIF_STEP(t4 + 0, p0a, p0b)
        if (t4 + 4 < TT) {
            p0a = *reinterpret_cast<const float4*>(out + (size_t)(t4 + 4) * STEP + rowb);
            p0b = *reinterpret_cast<const float4*>(out + (size_t)(t4 + 4) * STEP + rowb + 4);
        }
        LIF_STEP(t4 + 1, p1a, p1b)
        if (t4 + 5 < TT) {
            p1a = *reinterpret_cast<const float4*>(out + (size_t)(t4 + 5) * STEP + rowb);
            p1b = *reinterpret_cast<const float4*>(out + (size_t)(t4 + 5) * STEP + rowb + 4);
        }
        LIF_STEP(t4 + 2, p2a, p2b)
        if (t4 + 6 < TT) {
            p2a = *reinterpret_cast<const float4*>(out + (size_t)(t4 + 6) * STEP + rowb);
            p2b = *reinterpret_cast<const float4*>(out + (size_t)(t4 + 6) * STEP + rowb + 4);
        }
        LIF_STEP(t4 + 3, p3a, p3b)
        if (t4 + 7 < TT) {
            p3a = *reinterpret_cast<const float4*>(out + (size_t)(t4 + 7) * STEP + rowb);
            p3b = *reinterpret_cast<const float4*>(out + (size_t)(t4 + 7) * STEP + rowb + 4);
        }
    }
#undef LIF_STEP
}

extern "C" void kernel_launch(void* const* d_in, const int* in_sizes, int n_in,
                              void* d_out, int out_size, void* d_ws, size_t ws_size,
                              hipStream_t stream) {
    const float* x  = (const float*)d_in[0];
    const float* h1 = (const float*)d_in[1];
    const float* r1 = (const float*)d_in[2];
    float* out = (float*)d_out;
    (void)in_sizes; (void)n_in; (void)out_size;

    if (ws_size >= WS_NEED) {
        unsigned short* wsH = (unsigned short*)d_ws;
        unsigned short* wsL = wsH + (size_t)KIN * NRN;
        split_h<<<dim3(KIN), dim3(NRN), 0, stream>>>(h1, wsH, wsL);
        lif_gemm<true><<<dim3(NBLK), dim3(256), 0, stream>>>(x, h1, wsH, wsL, out);
    } else {
        lif_gemm<false><<<dim3(NBLK), dim3(256), 0, stream>>>(x, h1, nullptr, nullptr, out);
    }
    lif_scan<<<dim3(BSZ), dim3(64), 0, stream>>>(r1, out);
}

// Round 15
// 393.097 us; speedup vs baseline: 1.6840x; 1.6840x over previous
//
#include <hip/hip_runtime.h>

// LIF sim, three-phase:
//   0) split_h: pre-split h1 into bf16 hi/lo planes in d_ws ([kt][nb] 8KB
//      chunks, the gemm's swizzled B-LDS image).
//   1) lif_gemm<true>: aS = X @ H via bf16 3-product-split MFMA
//      (xh·hh + xh·hl + xl·hh), f32 accumulate, cvt_pk A-split, conflict-free
//      B copy, XCD swizzle, setprio around MFMA cluster. (R11/R13 verified.)
//   2) lif_scan: verified 512-thread scan (f64 state, LDS smask, depth-4
//      prefetch) + per-wave flag byte: dense steps read ONE u64 flag instead
//      of the 64B mask + 8 popcounts. Sparse path = bit-identical gather.
typedef __attribute__((ext_vector_type(8))) short short8;
typedef __attribute__((ext_vector_type(4))) float f32x4;

constexpr int BSZ = 256;
constexpr int NRN = 512;
constexpr int KIN = 512;
constexpr int TT  = 500;
constexpr int BM  = 128;   // m-tile (rows of x)
constexpr int BN  = 128;   // n-tile (neuron cols)
constexpr int KT  = 32;    // k-tile
constexpr int NBLK = (TT * BSZ / BM) * (NRN / BN);   // 4000
constexpr size_t WS_NEED = (size_t)2 * KIN * NRN * sizeof(unsigned short); // 1 MB

__device__ __forceinline__ unsigned short bf16rne(float f) {
    unsigned u = __float_as_uint(f);
    u += 0x7FFFu + ((u >> 16) & 1u);
    return (unsigned short)(u >> 16);
}
__device__ __forceinline__ float bf16f(unsigned short s) {
    return __uint_as_float(((unsigned)s) << 16);
}
// packed RNE bf16 pair: low16 = bf16(a), high16 = bf16(b). Bit-identical to bf16rne.
__device__ __forceinline__ unsigned cvtpk(float a, float b) {
    unsigned r;
    asm("v_cvt_pk_bf16_f32 %0, %1, %2" : "=v"(r) : "v"(a), "v"(b));
    return r;
}

// h1[k][n] -> hi/lo bf16 planes, laid out as the gemm's B-LDS image:
// chunk (kt*4+nb) of 8192 B; byte = ((nl*64+koct*16) ^ (((nl>>1)&3)<<4)) + 2*i
__global__ __launch_bounds__(512)
void split_h(const float* __restrict__ h1,
             unsigned short* __restrict__ wsH,
             unsigned short* __restrict__ wsL)
{
    const int k = blockIdx.x;          // 0..511
    const int n = threadIdx.x;         // 0..511 (coalesced read)
    const float v = h1[(size_t)k * NRN + n];
    const unsigned short h  = bf16rne(v);
    const unsigned short lo = bf16rne(v - bf16f(h));
    const int kt = k >> 5, koct = (k >> 3) & 3, i = k & 7;
    const int nb = n >> 7, nl = n & 127;
    const int byte = (kt * 4 + nb) * 8192 +
                     ((nl * 64 + koct * 16) ^ (((nl >> 1) & 3) << 4)) + i * 2;
    *reinterpret_cast<unsigned short*>((char*)wsH + byte) = h;
    *reinterpret_cast<unsigned short*>((char*)wsL + byte) = lo;
}

template<bool PS>
__global__ __launch_bounds__(256)
void lif_gemm(const float* __restrict__ x,
              const float* __restrict__ h1,
              const unsigned short* __restrict__ wsH,
              const unsigned short* __restrict__ wsL,
              float* __restrict__ out)
{
    // bf16 tiles, XOR-swizzled (byte ^= ((row>>1)&3)<<4): 4 x 8 KB = 32 KB
    __shared__ short AhS[BM * KT], AlS[BM * KT], BhS[BN * KT], BlS[BN * KT];

    const int tid  = threadIdx.x;
    const int l    = tid & 63;
    const int w    = tid >> 6;           // wave 0..3
    const int wm   = (w & 1) * 64;       // wave m-offset
    const int wn   = (w >> 1) * 64;      // wave n-offset
    const int lrow = l & 15;
    const int loct = l >> 4;             // k-octet 0..3

    // XCD-chunked bijective swizzle: 4000 = 8 x 500, 500 % 4 == 0 so the
    // 4 n-blocks of each m-tile stay inside one XCD's chunk (shared L2).
    const int nid = (blockIdx.x & 7) * (NBLK / 8) + (blockIdx.x >> 3);
    const size_t m0 = (size_t)(nid >> 2) * BM;
    const int    nb = nid & 3;
    const int    n0 = nb * BN;

    f32x4 acc[4][4];
    #pragma unroll
    for (int i = 0; i < 4; ++i)
        #pragma unroll
        for (int j = 0; j < 4; ++j) acc[i][j] = (f32x4)0.0f;

    for (int kt = 0; kt < KIN / KT; ++kt) {
        // ---- stage B (independent loads issue first, overlap A conversion) ----
        if (PS) {
            // linear conflict-free copy: 16B/lane consecutive
            const float4* sH = reinterpret_cast<const float4*>(
                (const char*)wsH + (kt * 4 + nb) * 8192);
            const float4* sL = reinterpret_cast<const float4*>(
                (const char*)wsL + (kt * 4 + nb) * 8192);
            float4* dH = reinterpret_cast<float4*>(BhS);
            float4* dL = reinterpret_cast<float4*>(BlS);
            dH[tid]       = sH[tid];
            dH[256 + tid] = sH[256 + tid];
            dL[tid]       = sL[tid];
            dL[256 + tid] = sL[256 + tid];
        } else {
            #pragma unroll
            for (int u2 = 0; u2 < 2; ++u2) {
                const int u = u2 * 256 + tid;          // 0..511
                const int nl = u & 127, koct = u >> 7; // n-local, k-octet
                short8 hh, hl;
                #pragma unroll
                for (int i = 0; i < 8; ++i) {          // coalesced across nl
                    const float v = h1[(size_t)(kt * KT + koct * 8 + i) * NRN + n0 + nl];
                    const unsigned short h = bf16rne(v);
                    hh[i] = (short)h;
                    hl[i] = (short)bf16rne(v - bf16f(h));
                }
                const int byte = (nl * 64 + koct * 16) ^ (((nl >> 1) & 3) << 4);
                *reinterpret_cast<short8*>((char*)BhS + byte) = hh;
                *reinterpret_cast<short8*>((char*)BlS + byte) = hl;
            }
        }
        // ---- stage A: x[m0..m0+128][kt*32..+32] -> bf16 split via cvt_pk ----
        #pragma unroll
        for (int u4 = 0; u4 < 4; ++u4) {
            const int u = u4 * 256 + tid;         // 0..1023
            const int row = u >> 3, slot = u & 7; // row 0..127, float4 slot 0..7
            const float4 xv = *reinterpret_cast<const float4*>(
                x + (m0 + row) * KIN + kt * KT + slot * 4);
            // hi plane (RNE, bit-identical to bf16rne)
            const unsigned h01 = cvtpk(xv.x, xv.y);
            const unsigned h23 = cvtpk(xv.z, xv.w);
            // residuals: bf16f(lo16)=bits<<16, bf16f(hi16)=bits&0xFFFF0000
            const float r0 = xv.x - __uint_as_float(h01 << 16);
            const float r1v = xv.y - __uint_as_float(h01 & 0xFFFF0000u);
            const float r2 = xv.z - __uint_as_float(h23 << 16);
            const float r3 = xv.w - __uint_as_float(h23 & 0xFFFF0000u);
            const unsigned l01 = cvtpk(r0, r1v);
            const unsigned l23 = cvtpk(r2, r3);
            const unsigned long long hb = (unsigned long long)h01 | ((unsigned long long)h23 << 32);
            const unsigned long long lb = (unsigned long long)l01 | ((unsigned long long)l23 << 32);
            const int byte = (row * 64 + slot * 8) ^ (((row >> 1) & 3) << 4);
            *reinterpret_cast<unsigned long long*>((char*)AhS + byte) = hb;
            *reinterpret_cast<unsigned long long*>((char*)AlS + byte) = lb;
        }
        __syncthreads();

        // ---- fragment loads (ds_read_b128) ----
        short8 ah[4], al[4], bh[4], bl[4];
        #pragma unroll
        for (int mi = 0; mi < 4; ++mi) {
            const int row  = wm + mi * 16 + lrow;
            const int byte = (row * 64 + loct * 16) ^ (((row >> 1) & 3) << 4);
            ah[mi] = *reinterpret_cast<const short8*>((const char*)AhS + byte);
            al[mi] = *reinterpret_cast<const short8*>((const char*)AlS + byte);
        }
        #pragma unroll
        for (int ni = 0; ni < 4; ++ni) {
            const int nn   = wn + ni * 16 + lrow;
            const int byte = (nn * 64 + loct * 16) ^ (((nn >> 1) & 3) << 4);
            bh[ni] = *reinterpret_cast<const short8*>((const char*)BhS + byte);
            bl[ni] = *reinterpret_cast<const short8*>((const char*)BlS + byte);
        }

        // ---- 48 MFMA: 3-product split (xl·hl dropped, ~1e-4 class) ----
        __builtin_amdgcn_s_setprio(1);
        #pragma unroll
        for (int mi = 0; mi < 4; ++mi)
            #pragma unroll
            for (int ni = 0; ni < 4; ++ni) {
                acc[mi][ni] = __builtin_amdgcn_mfma_f32_16x16x32_bf16(ah[mi], bh[ni], acc[mi][ni], 0, 0, 0);
                acc[mi][ni] = __builtin_amdgcn_mfma_f32_16x16x32_bf16(ah[mi], bl[ni], acc[mi][ni], 0, 0, 0);
                acc[mi][ni] = __builtin_amdgcn_mfma_f32_16x16x32_bf16(al[mi], bh[ni], acc[mi][ni], 0, 0, 0);
            }
        __builtin_amdgcn_s_setprio(0);
        __syncthreads();
    }

    // ---- epilogue: C/D layout col=lane&15, row=(lane>>4)*4+j (m89-verified) ----
    #pragma unroll
    for (int mi = 0; mi < 4; ++mi)
        #pragma unroll
        for (int j = 0; j < 4; ++j) {
            const size_t row = m0 + wm + mi * 16 + loct * 4 + j;
            float* op = out + row * NRN + n0 + wn + lrow;
            #pragma unroll
            for (int ni = 0; ni < 4; ++ni)
                op[ni * 16] = acc[mi][ni][j];
        }
}

__global__ __launch_bounds__(512, 2)
void lif_scan(const float* __restrict__ r1,
              float* __restrict__ out)
{
    __shared__ unsigned long long smask[2][8];   // ping-pong 512-bit spike mask
    __shared__ unsigned long long flg[2];        // per-wave class bytes:
                                                 // 0xFF=full, 0x00=empty, 0x01=mixed

    const int n  = threadIdx.x;      // neuron
    const int b  = blockIdx.x;       // batch row
    const int wv = n >> 6;
    const int ln = n & 63;
    const size_t row = (size_t)b * NRN + n;
    constexpr size_t STEP = (size_t)BSZ * NRN;

    if (n < 16) ((unsigned long long*)smask)[n] = 0ULL;
    if (n < 2)  flg[n] = 0ULL;

    // f64 ascending-j column sum of r1 (dense recurrent fast path)
    double csum = 0.0;
    for (int j = 0; j < KIN; ++j)
        csum += (double)r1[(size_t)j * NRN + n];

    double V = 1.0, Is = 0.0, Ir = 0.0, cnt = 0.0;
    const double steady = 0.01 * (double)n;
    constexpr double kS = 0.1, kN = 0.05, DT = 0.001;

    // aS prefetch, depth 4 (named regs -> no scratch)
    float a0 = out[0 * STEP + row];
    float a1 = out[1 * STEP + row];
    float a2 = out[2 * STEP + row];
    float a3 = out[3 * STEP + row];
    __syncthreads();

#define LIF_STEP(T, AREG)                                                     \
    {                                                                         \
        const int t_ = (T);                                                   \
        const int p_ = t_ & 1;                                                \
        const unsigned long long f_ = flg[p_];        /* 1 broadcast read */  \
        double aR;                                                            \
        if (f_ == 0xFFFFFFFFFFFFFFFFULL) {            /* all 512 spiked */    \
            aR = csum;                                                        \
        } else if (f_ == 0ULL) {                      /* none spiked */       \
            aR = 0.0;                                                         \
        } else {                                      /* rare: full gather */ \
            aR = 0.0;                                                         \
            _Pragma("unroll")                                                 \
            for (int w = 0; w < 8; ++w) {                                     \
                unsigned long long m_ = smask[p_][w];                         \
                while (m_) {                          /* ascending j */       \
                    const int j = w * 64 + __builtin_ctzll(m_);               \
                    aR += (double)r1[(size_t)j * NRN + n];                    \
                    m_ &= m_ - 1;                                             \
                }                                                             \
            }                                                                 \
        }                                                                     \
        Is = Is - kS * Is + (double)(AREG);            /* gain_syn = 1 */     \
        Ir = Ir - kS * Ir + 0.5 * aR;                  /* gain_syn_rec */     \
        double Vn = V - kN * V + DT * (Is + Ir + steady);                     \
        Vn = fmax(Vn, 0.0);                                                   \
        const bool sp = (Vn - 1.0) > 0.0;                                     \
        cnt = sp ? 2.0 : (cnt - 1.0);                  /* REFR = 2 */         \
        V = sp ? 0.0 : ((cnt <= 0.0) ? Vn : 0.0);                             \
        out[(size_t)t_ * STEP + row] = sp ? 1.0f : 0.0f;                      \
        const unsigned long long bal = __ballot(sp);                          \
        if (ln == 0) {                                                        \
            smask[p_ ^ 1][wv] = bal;                                          \
            const unsigned char fb =                                          \
                (bal == 0xFFFFFFFFFFFFFFFFULL) ? 0xFFu                        \
                : ((bal == 0ULL) ? 0x00u : 0x01u);                            \
            ((unsigned char*)&flg[p_ ^ 1])[wv] = fb;                          \
        }                                                                     \
        __syncthreads();                                                      \
    }

    for (int t4 = 0; t4 < TT; t4 += 4) {
        LIF_STEP(t4 + 0, a0)
        a0 = (t4 + 4 < TT) ? out[(size_t)(t4 + 4) * STEP + row] : 0.0f;
        LIF_STEP(t4 + 1, a1)
        a1 = (t4 + 5 < TT) ? out[(size_t)(t4 + 5) * STEP + row] : 0.0f;
        LIF_STEP(t4 + 2, a2)
        a2 = (t4 + 6 < TT) ? out[(size_t)(t4 + 6) * STEP + row] : 0.0f;
        LIF_STEP(t4 + 3, a3)
        a3 = (t4 + 7 < TT) ? out[(size_t)(t4 + 7) * STEP + row] : 0.0f;
    }
#undef LIF_STEP
}

extern "C" void kernel_launch(void* const* d_in, const int* in_sizes, int n_in,
                              void* d_out, int out_size, void* d_ws, size_t ws_size,
                              hipStream_t stream) {
    const float* x  = (const float*)d_in[0];
    const float* h1 = (const float*)d_in[1];
    const float* r1 = (const float*)d_in[2];
    float* out = (float*)d_out;
    (void)in_sizes; (void)n_in; (void)out_size;

    if (ws_size >= WS_NEED) {
        unsigned short* wsH = (unsigned short*)d_ws;
        unsigned short* wsL = wsH + (size_t)KIN * NRN;
        split_h<<<dim3(KIN), dim3(NRN), 0, stream>>>(h1, wsH, wsL);
        lif_gemm<true><<<dim3(NBLK), dim3(256), 0, stream>>>(x, h1, wsH, wsL, out);
    } else {
        lif_gemm<false><<<dim3(NBLK), dim3(256), 0, stream>>>(x, h1, nullptr, nullptr, out);
    }
    lif_scan<<<dim3(BSZ), dim3(512), 0, stream>>>(r1, out);
}

// Round 16
// 335.703 us; speedup vs baseline: 1.9719x; 1.1710x over previous
//
#include <hip/hip_runtime.h>

// LIF sim, three-phase:
//   0) split_h: pre-split h1 into bf16 hi/lo planes in d_ws ([kt][nb] 8KB
//      chunks, the gemm's swizzled B-LDS image).           (R15 verbatim)
//   1) lif_gemm<true>: aS = X @ H via bf16 3-product-split MFMA.
//                                                           (R15 verbatim)
//   2) lif_scan: 512-thread scan, SPECULATIVE 8-STEP BATCHES: when the spike
//      mask is full at a batch boundary, run 8 barrier-free dense steps
//      (aR = csum, identical arithmetic), verify with one ballot+barrier;
//      on failure restore checkpoint and replay via the verified STD path.
typedef __attribute__((ext_vector_type(8))) short short8;
typedef __attribute__((ext_vector_type(4))) float f32x4;

constexpr int BSZ = 256;
constexpr int NRN = 512;
constexpr int KIN = 512;
constexpr int TT  = 500;
constexpr int BM  = 128;   // m-tile (rows of x)
constexpr int BN  = 128;   // n-tile (neuron cols)
constexpr int KT  = 32;    // k-tile
constexpr int NBLK = (TT * BSZ / BM) * (NRN / BN);   // 4000
constexpr size_t WS_NEED = (size_t)2 * KIN * NRN * sizeof(unsigned short); // 1 MB
constexpr unsigned long long FULLM = 0xFFFFFFFFFFFFFFFFULL;

__device__ __forceinline__ unsigned short bf16rne(float f) {
    unsigned u = __float_as_uint(f);
    u += 0x7FFFu + ((u >> 16) & 1u);
    return (unsigned short)(u >> 16);
}
__device__ __forceinline__ float bf16f(unsigned short s) {
    return __uint_as_float(((unsigned)s) << 16);
}
// packed RNE bf16 pair: low16 = bf16(a), high16 = bf16(b). Bit-identical to bf16rne.
__device__ __forceinline__ unsigned cvtpk(float a, float b) {
    unsigned r;
    asm("v_cvt_pk_bf16_f32 %0, %1, %2" : "=v"(r) : "v"(a), "v"(b));
    return r;
}

// h1[k][n] -> hi/lo bf16 planes, laid out as the gemm's B-LDS image:
// chunk (kt*4+nb) of 8192 B; byte = ((nl*64+koct*16) ^ (((nl>>1)&3)<<4)) + 2*i
__global__ __launch_bounds__(512)
void split_h(const float* __restrict__ h1,
             unsigned short* __restrict__ wsH,
             unsigned short* __restrict__ wsL)
{
    const int k = blockIdx.x;          // 0..511
    const int n = threadIdx.x;         // 0..511 (coalesced read)
    const float v = h1[(size_t)k * NRN + n];
    const unsigned short h  = bf16rne(v);
    const unsigned short lo = bf16rne(v - bf16f(h));
    const int kt = k >> 5, koct = (k >> 3) & 3, i = k & 7;
    const int nb = n >> 7, nl = n & 127;
    const int byte = (kt * 4 + nb) * 8192 +
                     ((nl * 64 + koct * 16) ^ (((nl >> 1) & 3) << 4)) + i * 2;
    *reinterpret_cast<unsigned short*>((char*)wsH + byte) = h;
    *reinterpret_cast<unsigned short*>((char*)wsL + byte) = lo;
}

template<bool PS>
__global__ __launch_bounds__(256)
void lif_gemm(const float* __restrict__ x,
              const float* __restrict__ h1,
              const unsigned short* __restrict__ wsH,
              const unsigned short* __restrict__ wsL,
              float* __restrict__ out)
{
    // bf16 tiles, XOR-swizzled (byte ^= ((row>>1)&3)<<4): 4 x 8 KB = 32 KB
    __shared__ short AhS[BM * KT], AlS[BM * KT], BhS[BN * KT], BlS[BN * KT];

    const int tid  = threadIdx.x;
    const int l    = tid & 63;
    const int w    = tid >> 6;           // wave 0..3
    const int wm   = (w & 1) * 64;       // wave m-offset
    const int wn   = (w >> 1) * 64;      // wave n-offset
    const int lrow = l & 15;
    const int loct = l >> 4;             // k-octet 0..3

    // XCD-chunked bijective swizzle: 4000 = 8 x 500, 500 % 4 == 0 so the
    // 4 n-blocks of each m-tile stay inside one XCD's chunk (shared L2).
    const int nid = (blockIdx.x & 7) * (NBLK / 8) + (blockIdx.x >> 3);
    const size_t m0 = (size_t)(nid >> 2) * BM;
    const int    nb = nid & 3;
    const int    n0 = nb * BN;

    f32x4 acc[4][4];
    #pragma unroll
    for (int i = 0; i < 4; ++i)
        #pragma unroll
        for (int j = 0; j < 4; ++j) acc[i][j] = (f32x4)0.0f;

    for (int kt = 0; kt < KIN / KT; ++kt) {
        // ---- stage B (independent loads issue first, overlap A conversion) ----
        if (PS) {
            // linear conflict-free copy: 16B/lane consecutive
            const float4* sH = reinterpret_cast<const float4*>(
                (const char*)wsH + (kt * 4 + nb) * 8192);
            const float4* sL = reinterpret_cast<const float4*>(
                (const char*)wsL + (kt * 4 + nb) * 8192);
            float4* dH = reinterpret_cast<float4*>(BhS);
            float4* dL = reinterpret_cast<float4*>(BlS);
            dH[tid]       = sH[tid];
            dH[256 + tid] = sH[256 + tid];
            dL[tid]       = sL[tid];
            dL[256 + tid] = sL[256 + tid];
        } else {
            #pragma unroll
            for (int u2 = 0; u2 < 2; ++u2) {
                const int u = u2 * 256 + tid;          // 0..511
                const int nl = u & 127, koct = u >> 7; // n-local, k-octet
                short8 hh, hl;
                #pragma unroll
                for (int i = 0; i < 8; ++i) {          // coalesced across nl
                    const float v = h1[(size_t)(kt * KT + koct * 8 + i) * NRN + n0 + nl];
                    const unsigned short h = bf16rne(v);
                    hh[i] = (short)h;
                    hl[i] = (short)bf16rne(v - bf16f(h));
                }
                const int byte = (nl * 64 + koct * 16) ^ (((nl >> 1) & 3) << 4);
                *reinterpret_cast<short8*>((char*)BhS + byte) = hh;
                *reinterpret_cast<short8*>((char*)BlS + byte) = hl;
            }
        }
        // ---- stage A: x[m0..m0+128][kt*32..+32] -> bf16 split via cvt_pk ----
        #pragma unroll
        for (int u4 = 0; u4 < 4; ++u4) {
            const int u = u4 * 256 + tid;         // 0..1023
            const int row = u >> 3, slot = u & 7; // row 0..127, float4 slot 0..7
            const float4 xv = *reinterpret_cast<const float4*>(
                x + (m0 + row) * KIN + kt * KT + slot * 4);
            // hi plane (RNE, bit-identical to bf16rne)
            const unsigned h01 = cvtpk(xv.x, xv.y);
            const unsigned h23 = cvtpk(xv.z, xv.w);
            // residuals: bf16f(lo16)=bits<<16, bf16f(hi16)=bits&0xFFFF0000
            const float r0 = xv.x - __uint_as_float(h01 << 16);
            const float r1v = xv.y - __uint_as_float(h01 & 0xFFFF0000u);
            const float r2 = xv.z - __uint_as_float(h23 << 16);
            const float r3 = xv.w - __uint_as_float(h23 & 0xFFFF0000u);
            const unsigned l01 = cvtpk(r0, r1v);
            const unsigned l23 = cvtpk(r2, r3);
            const unsigned long long hb = (unsigned long long)h01 | ((unsigned long long)h23 << 32);
            const unsigned long long lb = (unsigned long long)l01 | ((unsigned long long)l23 << 32);
            const int byte = (row * 64 + slot * 8) ^ (((row >> 1) & 3) << 4);
            *reinterpret_cast<unsigned long long*>((char*)AhS + byte) = hb;
            *reinterpret_cast<unsigned long long*>((char*)AlS + byte) = lb;
        }
        __syncthreads();

        // ---- fragment loads (ds_read_b128) ----
        short8 ah[4], al[4], bh[4], bl[4];
        #pragma unroll
        for (int mi = 0; mi < 4; ++mi) {
            const int row  = wm + mi * 16 + lrow;
            const int byte = (row * 64 + loct * 16) ^ (((row >> 1) & 3) << 4);
            ah[mi] = *reinterpret_cast<const short8*>((const char*)AhS + byte);
            al[mi] = *reinterpret_cast<const short8*>((const char*)AlS + byte);
        }
        #pragma unroll
        for (int ni = 0; ni < 4; ++ni) {
            const int nn   = wn + ni * 16 + lrow;
            const int byte = (nn * 64 + loct * 16) ^ (((nn >> 1) & 3) << 4);
            bh[ni] = *reinterpret_cast<const short8*>((const char*)BhS + byte);
            bl[ni] = *reinterpret_cast<const short8*>((const char*)BlS + byte);
        }

        // ---- 48 MFMA: 3-product split (xl·hl dropped, ~1e-4 class) ----
        __builtin_amdgcn_s_setprio(1);
        #pragma unroll
        for (int mi = 0; mi < 4; ++mi)
            #pragma unroll
            for (int ni = 0; ni < 4; ++ni) {
                acc[mi][ni] = __builtin_amdgcn_mfma_f32_16x16x32_bf16(ah[mi], bh[ni], acc[mi][ni], 0, 0, 0);
                acc[mi][ni] = __builtin_amdgcn_mfma_f32_16x16x32_bf16(ah[mi], bl[ni], acc[mi][ni], 0, 0, 0);
                acc[mi][ni] = __builtin_amdgcn_mfma_f32_16x16x32_bf16(al[mi], bh[ni], acc[mi][ni], 0, 0, 0);
            }
        __builtin_amdgcn_s_setprio(0);
        __syncthreads();
    }

    // ---- epilogue: C/D layout col=lane&15, row=(lane>>4)*4+j (m89-verified) ----
    #pragma unroll
    for (int mi = 0; mi < 4; ++mi)
        #pragma unroll
        for (int j = 0; j < 4; ++j) {
            const size_t row = m0 + wm + mi * 16 + loct * 4 + j;
            float* op = out + row * NRN + n0 + wn + lrow;
            #pragma unroll
            for (int ni = 0; ni < 4; ++ni)
                op[ni * 16] = acc[mi][ni][j];
        }
}

__global__ __launch_bounds__(512, 2)
void lif_scan(const float* __restrict__ r1,
              float* __restrict__ out)
{
    __shared__ unsigned long long smask[2][8];   // ping-pong 512-bit spike mask
    __shared__ unsigned long long flg[2];        // per-wave class bytes
    __shared__ unsigned long long vflg;          // batch verdict bytes

    const int n  = threadIdx.x;      // neuron
    const int b  = blockIdx.x;       // batch row
    const int wv = n >> 6;
    const int ln = n & 63;
    const size_t row = (size_t)b * NRN + n;
    constexpr size_t STEP = (size_t)BSZ * NRN;

    if (n < 16) ((unsigned long long*)smask)[n] = 0ULL;
    if (n < 2)  flg[n] = 0ULL;

    // f64 ascending-j column sum of r1 (dense recurrent fast path)
    double csum = 0.0;
    for (int j = 0; j < KIN; ++j)
        csum += (double)r1[(size_t)j * NRN + n];

    double V = 1.0, Is = 0.0, Ir = 0.0, cnt = 0.0;
    const double steady = 0.01 * (double)n;
    constexpr double kS = 0.1, kN = 0.05, DT = 0.001;

    float cur[8], nxt[8];
    #pragma unroll
    for (int i = 0; i < 8; ++i) cur[i] = out[(size_t)i * STEP + row];
    __syncthreads();

    // Verified per-step path (R15): flag-classified recurrent term, LDS mask
    // exchange, one barrier per step.
#define STD_STEP(T, AREG)                                                     \
    {                                                                         \
        const int t_ = (T);                                                   \
        const int p_ = t_ & 1;                                                \
        const unsigned long long f_ = flg[p_];                                \
        double aR;                                                            \
        if (f_ == FULLM) {                                                    \
            aR = csum;                                                        \
        } else if (f_ == 0ULL) {                                              \
            aR = 0.0;                                                         \
        } else {                                                              \
            aR = 0.0;                                                         \
            _Pragma("unroll")                                                 \
            for (int w = 0; w < 8; ++w) {                                     \
                unsigned long long m_ = smask[p_][w];                         \
                while (m_) {                          /* ascending j */       \
                    const int j = w * 64 + __builtin_ctzll(m_);               \
                    aR += (double)r1[(size_t)j * NRN + n];                    \
                    m_ &= m_ - 1;                                             \
                }                                                             \
            }                                                                 \
        }                                                                     \
        Is = Is - kS * Is + (double)(AREG);            /* gain_syn = 1 */     \
        Ir = Ir - kS * Ir + 0.5 * aR;                  /* gain_syn_rec */     \
        double Vn = V - kN * V + DT * (Is + Ir + steady);                     \
        Vn = fmax(Vn, 0.0);                                                   \
        const bool sp = (Vn - 1.0) > 0.0;                                     \
        cnt = sp ? 2.0 : (cnt - 1.0);                  /* REFR = 2 */         \
        V = sp ? 0.0 : ((cnt <= 0.0) ? Vn : 0.0);                             \
        out[(size_t)t_ * STEP + row] = sp ? 1.0f : 0.0f;                      \
        const unsigned long long bal = __ballot(sp);                          \
        if (ln == 0) {                                                        \
            smask[p_ ^ 1][wv] = bal;                                          \
            const unsigned char fb =                                          \
                (bal == FULLM) ? 0xFFu : ((bal == 0ULL) ? 0x00u : 0x01u);     \
            ((unsigned char*)&flg[p_ ^ 1])[wv] = fb;                          \
        }                                                                     \
        __syncthreads();                                                      \
    }

    for (int t0 = 0; t0 < 496; t0 += 8) {      // 62 batches of 8
        // prefetch next batch's aS (drains at this batch's barrier(s))
        #pragma unroll
        for (int i = 0; i < 8; ++i)
            nxt[i] = (t0 + 8 + i < TT) ? out[(size_t)(t0 + 8 + i) * STEP + row] : 0.0f;

        if (flg[t0 & 1] == FULLM) {
            // ---- speculative dense batch: no barriers, aR = csum each step ----
            const double Vc = V, Isc = Is, Irc = Ir, cc = cnt;
            bool allm = true;
            #pragma unroll
            for (int i = 0; i < 8; ++i) {
                Is = Is - kS * Is + (double)cur[i];
                Ir = Ir - kS * Ir + 0.5 * csum;
                double Vn = V - kN * V + DT * (Is + Ir + steady);
                Vn = fmax(Vn, 0.0);
                const bool sp = (Vn - 1.0) > 0.0;
                allm &= sp;
                cnt = sp ? 2.0 : (cnt - 1.0);
                V = sp ? 0.0 : ((cnt <= 0.0) ? Vn : 0.0);
                out[(size_t)(t0 + i) * STEP + row] = sp ? 1.0f : 0.0f;
            }
            const unsigned long long bal = __ballot(allm);
            if (ln == 0) {
                ((unsigned char*)&vflg)[wv] = (bal == FULLM) ? 0xFFu : 0x00u;
                // optimistic publish for next batch ((t0+8)&1 == t0&1)
                smask[t0 & 1][wv] = FULLM;
                ((unsigned char*)&flg[t0 & 1])[wv] = 0xFFu;
            }
            __syncthreads();
            if (vflg != FULLM) {
                // rollback + replay through the verified path.
                // Entry mask for step t0 is full: smask/flg[t0&1] == FULL
                // (just rewritten above, matching the verified entry state).
                V = Vc; Is = Isc; Ir = Irc; cnt = cc;
                STD_STEP(t0 + 0, cur[0])
                STD_STEP(t0 + 1, cur[1])
                STD_STEP(t0 + 2, cur[2])
                STD_STEP(t0 + 3, cur[3])
                STD_STEP(t0 + 4, cur[4])
                STD_STEP(t0 + 5, cur[5])
                STD_STEP(t0 + 6, cur[6])
                STD_STEP(t0 + 7, cur[7])
            }
        } else {
            // ---- standard batch (transient / mixed masks) ----
            STD_STEP(t0 + 0, cur[0])
            STD_STEP(t0 + 1, cur[1])
            STD_STEP(t0 + 2, cur[2])
            STD_STEP(t0 + 3, cur[3])
            STD_STEP(t0 + 4, cur[4])
            STD_STEP(t0 + 5, cur[5])
            STD_STEP(t0 + 6, cur[6])
            STD_STEP(t0 + 7, cur[7])
        }

        #pragma unroll
        for (int i = 0; i < 8; ++i) cur[i] = nxt[i];
    }

    // tail: steps 496..499 through the verified path
    STD_STEP(496, cur[0])
    STD_STEP(497, cur[1])
    STD_STEP(498, cur[2])
    STD_STEP(499, cur[3])
#undef STD_STEP
}

extern "C" void kernel_launch(void* const* d_in, const int* in_sizes, int n_in,
                              void* d_out, int out_size, void* d_ws, size_t ws_size,
                              hipStream_t stream) {
    const float* x  = (const float*)d_in[0];
    const float* h1 = (const float*)d_in[1];
    const float* r1 = (const float*)d_in[2];
    float* out = (float*)d_out;
    (void)in_sizes; (void)n_in; (void)out_size;

    if (ws_size >= WS_NEED) {
        unsigned short* wsH = (unsigned short*)d_ws;
        unsigned short* wsL = wsH + (size_t)KIN * NRN;
        split_h<<<dim3(KIN), dim3(NRN), 0, stream>>>(h1, wsH, wsL);
        lif_gemm<true><<<dim3(NBLK), dim3(256), 0, stream>>>(x, h1, wsH, wsL, out);
    } else {
        lif_gemm<false><<<dim3(NBLK), dim3(256), 0, stream>>>(x, h1, nullptr, nullptr, out);
    }
    lif_scan<<<dim3(BSZ), dim3(512), 0, stream>>>(r1, out);
}